// Round 2
// baseline (256.569 us; speedup 1.0000x reference)
//
#include <hip/hip_runtime.h>
#include <hip/hip_cooperative_groups.h>

namespace cg = cooperative_groups;

#define N 8192
#define D 128
#define T64 64
#define NT64 (N / T64)   // 128 tile-rows; NPAIR = 128*129/2 = 8256
#define GBLK 512         // cooperative grid: 2 blocks/CU on 256 CUs
// 2048 waves cover 8256 pairs: w<64 -> 5 pairs (start=5w), else 4 (start=4w+64)

typedef __attribute__((ext_vector_type(4))) int intx4;
typedef unsigned long long u64;

static __device__ inline float softplus_of(const float* __restrict__ phi) {
    float p = phi[0];
    return (p > 20.f) ? p : log1pf(__expf(p));
}

// ---------------------------------------------------------------------------
// Scratch lives inside d_out (4 MB out region; scratch needs 1.0625 MB).
// d_ws untouched (unknown ws_size previously caused an OOB input corruption).
//   q8     : bytes  [0, N*D)   (1 MB)
//   sqv    : ints   after q8   (32 KB)
//   rowsum : floats after sqv  (32 KB)
//   acc    : out[N*D] (the IXT output slot doubles as the log-sum accumulator;
//            only thread gid==0 reads/finalizes it in P4, no aliasing race)
// Single cooperative kernel: P1 quant -> sync -> P2 gram -> sync ->
// P3 log-reduce -> sync -> P4 (out = x+var*noise overwrites scratch, IXT final)
// ---------------------------------------------------------------------------
__global__ __launch_bounds__(256, 2) void fused(
        const float* __restrict__ x, const float* __restrict__ phi,
        const float* __restrict__ noise, float* out) {
    signed char* q8   = (signed char*)out;                 // aliases out: no restrict
    int*         sqv    = (int*)(out + (size_t)N * D / 4);
    float*       rowsum = (float*)(sqv + N);
    float*       ixt    = out + (size_t)N * D;

    cg::grid_group grid = cg::this_grid();
    const int tid = threadIdx.x;
    const int gid = blockIdx.x * 256 + tid;     // 131072 threads == N*16 == N*D/8
    const float var = softplus_of(phi);

    // ---- P1: quantize q8 = int8(rint(16*x)), sqv = sum q^2, rowsum = 0 ----
    {
        int row = gid >> 4, gc = gid & 15;
        const float* xs = x + (size_t)row * D + gc * 8;
        float4 u = *(const float4*)xs, v = *(const float4*)(xs + 4);
        float f[8] = {u.x, u.y, u.z, u.w, v.x, v.y, v.z, v.w};
        u64 pack = 0;
        int s = 0;
        #pragma unroll
        for (int k = 0; k < 8; k++) {
            float c = fminf(fmaxf(f[k] * 16.f, -127.f), 127.f);
            int q = (int)rintf(c);
            s += q * q;
            pack |= ((u64)(q & 255)) << (8 * k);
        }
        *(u64*)&q8[(size_t)row * D + gc * 8] = pack;
        #pragma unroll
        for (int m = 1; m < 16; m <<= 1) s += __shfl_xor(s, m, 64);
        if (gc == 0) { sqv[row] = s; rowsum[row] = 0.f; }
        if (gid == 0) ixt[0] = 0.f;
    }
    grid.sync();

    // ---- P2: screened symmetric int8 Gram (proven body, 2048-wave map) ----
    {
        const int w    = blockIdx.x * 4 + (tid >> 6);
        const int lane = tid & 63;
        const int lrow = lane & 15;
        const int quad = lane >> 4;

        const int cnt = (w < 64) ? 5 : 4;
        int start     = (w < 64) ? 5 * w : 4 * w + 64;
        int ti = 0, rem = start, len = NT64;
        while (rem >= len) { rem -= len; ++ti; --len; }
        int tj = ti + rem;

        // p = exp(-0.5*(d2s/256)/var) = exp2(d2s * c2)
        const float c2 = ((-0.5f / var) * 1.4426950408889634f) * (1.f / 256.f);
        // prune iff contribution <= 2^-30  <=>  d2s >= 30/(-c2)
        const int Ts = (int)ceilf(30.f / (-c2));

        intx4 af[4][2], bf[4][2];
        int   sqi[4][4];
        int curTi = -1;

        #pragma unroll
        for (int nt = 0; nt < 4; nt++) {
            const signed char* br = q8 + (size_t)(tj * T64 + nt * 16 + lrow) * D + quad * 16;
            bf[nt][0] = *(const intx4*)br;
            bf[nt][1] = *(const intx4*)(br + 64);
        }

        for (int r = 0; r < cnt; ++r) {
            const int iB = ti * T64, jB = tj * T64;

            int sje[4];
            #pragma unroll
            for (int nt = 0; nt < 4; nt++)
                sje[nt] = sqv[jB + nt * 16 + lrow];

            if (ti != curTi) {
                #pragma unroll
                for (int mt = 0; mt < 4; mt++) {
                    const signed char* ar =
                        q8 + (size_t)(iB + mt * 16 + lrow) * D + quad * 16;
                    af[mt][0] = *(const intx4*)ar;
                    af[mt][1] = *(const intx4*)(ar + 64);
                }
                #pragma unroll
                for (int mt = 0; mt < 4; mt++)
                    #pragma unroll
                    for (int reg = 0; reg < 4; reg++)
                        sqi[mt][reg] = sqv[iB + mt * 16 + quad * 4 + reg];
                curTi = ti;
            }

            int nti = ti, ntj = tj + 1;
            if (ntj == NT64) { ++nti; ntj = nti; }
            const bool more = (r + 1 < cnt);

            #pragma unroll
            for (int nt = 0; nt < 4; nt++) {
                intx4 acc[4] = {};
                #pragma unroll
                for (int kk = 0; kk < 2; kk++)
                    #pragma unroll
                    for (int mt = 0; mt < 4; mt++)
                        acc[mt] = __builtin_amdgcn_mfma_i32_16x16x64_i8(
                            af[mt][kk], bf[nt][kk], acc[mt], 0, 0, 0);

                // prefetch next pair's bf[nt] (no barrier ever drains it)
                if (more) {
                    const signed char* br =
                        q8 + (size_t)(ntj * T64 + nt * 16 + lrow) * D + quad * 16;
                    bf[nt][0] = *(const intx4*)br;
                    bf[nt][1] = *(const intx4*)(br + 64);
                }

                // integer screen: min d2s over this nt-column
                // C/D layout: col = lane&15, row = quad*4 + reg  [learn_hip m89]
                const int sj = sje[nt];
                int mn = 0x7fffffff;
                #pragma unroll
                for (int mt = 0; mt < 4; mt++)
                    #pragma unroll
                    for (int reg = 0; reg < 4; reg++) {
                        int d2s = sqi[mt][reg] + sj - (acc[mt][reg] << 1);
                        mn = min(mn, d2s);
                    }

                if (__any(mn < Ts)) {
                    float colv = 0.f;
                    #pragma unroll
                    for (int mt = 0; mt < 4; mt++)
                        #pragma unroll
                        for (int reg = 0; reg < 4; reg++) {
                            int d2s = sqi[mt][reg] + sj - (acc[mt][reg] << 1);
                            float p = __builtin_amdgcn_exp2f((float)d2s * c2);
                            colv += p;
                            float rv = p;
                            rv += __shfl_xor(rv, 1, 64);
                            rv += __shfl_xor(rv, 2, 64);
                            rv += __shfl_xor(rv, 4, 64);
                            rv += __shfl_xor(rv, 8, 64);
                            if (lrow == 0)
                                atomicAdd(&rowsum[iB + mt * 16 + quad * 4 + reg], rv);
                        }
                    if (ti != tj) {
                        colv += __shfl_xor(colv, 16, 64);
                        colv += __shfl_xor(colv, 32, 64);
                        if (quad == 0)
                            atomicAdd(&rowsum[jB + nt * 16 + lrow], colv);
                    }
                }
            }

            ti = nti; tj = ntj;
        }
    }
    grid.sync();

    // ---- P3: distributed log-reduce into the IXT slot ----
    if (gid < N) {
        float l = logf(rowsum[gid]);
        #pragma unroll
        for (int m = 1; m < 64; m <<= 1) l += __shfl_xor(l, m, 64);
        if ((tid & 63) == 0) atomicAdd(ixt, l);
    }
    grid.sync();

    // ---- P4: out = x + var*noise (overwrites scratch); gid 0 finalizes IXT ----
    {
        const float* xs = x     + (size_t)gid * 8;
        const float* ns = noise + (size_t)gid * 8;
        float4 u  = *(const float4*)xs, v  = *(const float4*)(xs + 4);
        float4 nu = *(const float4*)ns, nv = *(const float4*)(ns + 4);
        float4 o0, o1;
        o0.x = u.x + var * nu.x; o0.y = u.y + var * nu.y;
        o0.z = u.z + var * nu.z; o0.w = u.w + var * nu.w;
        o1.x = v.x + var * nv.x; o1.y = v.y + var * nv.y;
        o1.z = v.z + var * nv.z; o1.w = v.w + var * nv.w;
        if (gid == 0) {
            float S = ixt[0];   // only gid 0 touches out[N*D] in P4: no race
            ixt[0] = (logf((float)N) - S / (float)N) * 1.4426950408889634f;
        }
        float* od = out + (size_t)gid * 8;
        *(float4*)od = o0; *(float4*)(od + 4) = o1;
    }
}

// ======================= fallback path (proven, round 1) ====================
__global__ __launch_bounds__(256) void k1_quant(
        const float* __restrict__ x,
        signed char* __restrict__ q8, int* __restrict__ sqv,
        float* __restrict__ rowsum) {
    int gid = blockIdx.x * 256 + threadIdx.x;
    int row = gid >> 4;
    int gc  = gid & 15;
    const float* xs = x + (size_t)row * D + gc * 8;
    float4 u = *(const float4*)xs, v = *(const float4*)(xs + 4);
    float f[8] = {u.x, u.y, u.z, u.w, v.x, v.y, v.z, v.w};
    u64 pack = 0;
    int s = 0;
    #pragma unroll
    for (int k = 0; k < 8; k++) {
        float c = fminf(fmaxf(f[k] * 16.f, -127.f), 127.f);
        int q = (int)rintf(c);
        s += q * q;
        pack |= ((u64)(q & 255)) << (8 * k);
    }
    *(u64*)&q8[(size_t)row * D + gc * 8] = pack;
    #pragma unroll
    for (int m = 1; m < 16; m <<= 1) s += __shfl_xor(s, m, 64);
    if (gc == 0) { sqv[row] = s; rowsum[row] = 0.f; }
}

__global__ __launch_bounds__(256, 3) void k2_gram(
        const signed char* __restrict__ q8, const float* __restrict__ phi,
        const int* __restrict__ sqv, float* __restrict__ rowsum) {
    const int w    = blockIdx.x * 4 + (threadIdx.x >> 6);
    const int lane = threadIdx.x & 63;
    const int lrow = lane & 15;
    const int quad = lane >> 4;
    const int cnt = (w < 2112) ? 3 : 2;
    int start     = (w < 2112) ? 3 * w : 2 * w + 2112;
    int ti = 0, rem = start, len = NT64;
    while (rem >= len) { rem -= len; ++ti; --len; }
    int tj = ti + rem;
    float var = softplus_of(phi);
    const float c2 = ((-0.5f / var) * 1.4426950408889634f) * (1.f / 256.f);
    const int Ts = (int)ceilf(30.f / (-c2));
    intx4 af[4][2], bf[4][2];
    int   sqi[4][4];
    int curTi = -1;
    #pragma unroll
    for (int nt = 0; nt < 4; nt++) {
        const signed char* br = q8 + (size_t)(tj * T64 + nt * 16 + lrow) * D + quad * 16;
        bf[nt][0] = *(const intx4*)br;
        bf[nt][1] = *(const intx4*)(br + 64);
    }
    for (int r = 0; r < cnt; ++r) {
        const int iB = ti * T64, jB = tj * T64;
        int sje[4];
        #pragma unroll
        for (int nt = 0; nt < 4; nt++)
            sje[nt] = sqv[jB + nt * 16 + lrow];
        if (ti != curTi) {
            #pragma unroll
            for (int mt = 0; mt < 4; mt++) {
                const signed char* ar =
                    q8 + (size_t)(iB + mt * 16 + lrow) * D + quad * 16;
                af[mt][0] = *(const intx4*)ar;
                af[mt][1] = *(const intx4*)(ar + 64);
            }
            #pragma unroll
            for (int mt = 0; mt < 4; mt++)
                #pragma unroll
                for (int reg = 0; reg < 4; reg++)
                    sqi[mt][reg] = sqv[iB + mt * 16 + quad * 4 + reg];
            curTi = ti;
        }
        int nti = ti, ntj = tj + 1;
        if (ntj == NT64) { ++nti; ntj = nti; }
        const bool more = (r + 1 < cnt);
        #pragma unroll
        for (int nt = 0; nt < 4; nt++) {
            intx4 acc[4] = {};
            #pragma unroll
            for (int kk = 0; kk < 2; kk++)
                #pragma unroll
                for (int mt = 0; mt < 4; mt++)
                    acc[mt] = __builtin_amdgcn_mfma_i32_16x16x64_i8(
                        af[mt][kk], bf[nt][kk], acc[mt], 0, 0, 0);
            if (more) {
                const signed char* br =
                    q8 + (size_t)(ntj * T64 + nt * 16 + lrow) * D + quad * 16;
                bf[nt][0] = *(const intx4*)br;
                bf[nt][1] = *(const intx4*)(br + 64);
            }
            const int sj = sje[nt];
            int mn = 0x7fffffff;
            #pragma unroll
            for (int mt = 0; mt < 4; mt++)
                #pragma unroll
                for (int reg = 0; reg < 4; reg++) {
                    int d2s = sqi[mt][reg] + sj - (acc[mt][reg] << 1);
                    mn = min(mn, d2s);
                }
            if (__any(mn < Ts)) {
                float colv = 0.f;
                #pragma unroll
                for (int mt = 0; mt < 4; mt++)
                    #pragma unroll
                    for (int reg = 0; reg < 4; reg++) {
                        int d2s = sqi[mt][reg] + sj - (acc[mt][reg] << 1);
                        float p = __builtin_amdgcn_exp2f((float)d2s * c2);
                        colv += p;
                        float rv = p;
                        rv += __shfl_xor(rv, 1, 64);
                        rv += __shfl_xor(rv, 2, 64);
                        rv += __shfl_xor(rv, 4, 64);
                        rv += __shfl_xor(rv, 8, 64);
                        if (lrow == 0)
                            atomicAdd(&rowsum[iB + mt * 16 + quad * 4 + reg], rv);
                    }
                if (ti != tj) {
                    colv += __shfl_xor(colv, 16, 64);
                    colv += __shfl_xor(colv, 32, 64);
                    if (quad == 0)
                        atomicAdd(&rowsum[jB + nt * 16 + lrow], colv);
                }
            }
        }
        ti = nti; tj = ntj;
    }
}

__global__ __launch_bounds__(1024) void k3_final(
        const float* __restrict__ rowsum, float* __restrict__ out_ixt) {
    __shared__ float red[16];
    int t = threadIdx.x;
    float local = 0.f;
    for (int i = t; i < N; i += 1024) local += logf(rowsum[i]);
    #pragma unroll
    for (int m = 1; m < 64; m <<= 1) local += __shfl_xor(local, m, 64);
    if ((t & 63) == 0) red[t >> 6] = local;
    __syncthreads();
    if (t < 16) {
        float v = red[t];
        #pragma unroll
        for (int m = 1; m < 16; m <<= 1) v += __shfl_xor(v, m, 64);
        if (t == 0) {
            float kde = v / (float)N;
            out_ixt[0] = (logf((float)N) - kde) * 1.4426950408889634f;
        }
    }
}

__global__ __launch_bounds__(256) void k4_out(
        const float* __restrict__ x, const float* __restrict__ phi,
        const float* __restrict__ noise, float* __restrict__ out) {
    int gid = blockIdx.x * 256 + threadIdx.x;
    float var = softplus_of(phi);
    const float* xs = x     + (size_t)gid * 8;
    const float* ns = noise + (size_t)gid * 8;
    float4 u  = *(const float4*)xs, v  = *(const float4*)(xs + 4);
    float4 nu = *(const float4*)ns, nv = *(const float4*)(ns + 4);
    float4 o0, o1;
    o0.x = u.x + var * nu.x; o0.y = u.y + var * nu.y;
    o0.z = u.z + var * nu.z; o0.w = u.w + var * nu.w;
    o1.x = v.x + var * nv.x; o1.y = v.y + var * nv.y;
    o1.z = v.z + var * nv.z; o1.w = v.w + var * nv.w;
    float* od = out + (size_t)gid * 8;
    *(float4*)od = o0; *(float4*)(od + 4) = o1;
}

extern "C" void kernel_launch(void* const* d_in, const int* in_sizes, int n_in,
                              void* d_out, int out_size, void* d_ws, size_t ws_size,
                              hipStream_t stream) {
    const float* x     = (const float*)d_in[0];
    const float* phi   = (const float*)d_in[1];
    const float* noise = (const float*)d_in[2];
    float* out = (float*)d_out;

    void* args[] = {(void*)&x, (void*)&phi, (void*)&noise, (void*)&out};
    hipError_t e = hipLaunchCooperativeKernel(
        reinterpret_cast<void*>(fused), dim3(GBLK), dim3(256), args, 0, stream);
    if (e != hipSuccess) {
        (void)hipGetLastError();  // clear sticky error, use proven 4-kernel path
        signed char* q8  = (signed char*)out;
        int*   sqv    = (int*)(out + (size_t)N * D / 4);
        float* rowsum = (float*)(sqv + N);
        k1_quant<<<(N * 16) / 256, 256, 0, stream>>>(x, q8, sqv, rowsum);
        k2_gram<<<768, 256, 0, stream>>>(q8, phi, sqv, rowsum);
        k3_final<<<1, 1024, 0, stream>>>(rowsum, out + (size_t)N * D);
        k4_out<<<(N * D / 8) / 256, 256, 0, stream>>>(x, phi, noise, out);
    }
}

// Round 3
// 111.846 us; speedup vs baseline: 2.2939x; 2.2939x over previous
//
#include <hip/hip_runtime.h>

#define N 8192
#define D 128
#define T64 64
#define NT64 (N / T64)   // 128 tile-rows; NPAIR = 128*129/2 = 8256 = 2112*3 + 960*2
#define PREFIX 2192      // out rows [0,PREFIX) overlap scratch -> written by k4 last
#define K2BLK 768        // 3 blocks/CU, 3072 waves

typedef __attribute__((ext_vector_type(4))) int intx4;
typedef unsigned long long u64;

static __device__ inline float softplus_of(const float* __restrict__ phi) {
    float p = phi[0];
    return (p > 20.f) ? p : log1pf(__expf(p));
}

// ---------------------------------------------------------------------------
// Scratch lives inside d_out (4 MB out region; scratch needs ~1.07 MB).
// d_ws is never touched.
//   q8      : bytes  [0, N*D)      (1 MB)
//   sqv     : N ints                (32 KB)
//   rowsum  : N floats              (32 KB)
//   sqmin16 : N/16 ints             (2 KB)   per-16-row min of sqv (for screen)
//   counter : 1 int                 (last-block-done for the fused log-reduce)
// Total 1,116,168 B < PREFIX*512 = 1,122,304 B.
// k1: quant + sqv + sqmin16 + zero(rowsum,counter) + out rows [PREFIX,N)
// k2: screened gram; LAST block computes IXT (replaces old k3)
// k4: out rows [0,PREFIX) — overwrites scratch after k2 consumed it
// ---------------------------------------------------------------------------

__global__ __launch_bounds__(256) void k1_prep(
        const float* __restrict__ x, const float* __restrict__ phi,
        const float* __restrict__ noise, float* __restrict__ out,
        signed char* __restrict__ q8, int* __restrict__ sqv,
        float* __restrict__ rowsum, int* __restrict__ sqmin16,
        int* __restrict__ counter) {
    __shared__ int smin[16];
    int tid = threadIdx.x;
    int gid = blockIdx.x * 256 + tid;
    int row = gid >> 4;       // block covers rows [16b, 16b+16)
    int gc  = gid & 15;

    const float* xs = x + (size_t)row * D + gc * 8;
    float4 u = *(const float4*)xs, v = *(const float4*)(xs + 4);

    float f[8] = {u.x, u.y, u.z, u.w, v.x, v.y, v.z, v.w};
    u64 pack = 0;
    int s = 0;
    #pragma unroll
    for (int k = 0; k < 8; k++) {
        float c = fminf(fmaxf(f[k] * 16.f, -127.f), 127.f);
        int q = (int)rintf(c);
        s += q * q;
        pack |= ((u64)(q & 255)) << (8 * k);
    }
    *(u64*)&q8[(size_t)row * D + gc * 8] = pack;

    #pragma unroll
    for (int m = 1; m < 16; m <<= 1) s += __shfl_xor(s, m, 64);
    if (gc == 0) { sqv[row] = s; rowsum[row] = 0.f; smin[tid >> 4] = s; }
    if (gid == 0) counter[0] = 0;
    __syncthreads();
    if (tid == 0) {
        int m = smin[0];
        #pragma unroll
        for (int k = 1; k < 16; k++) m = min(m, smin[k]);
        sqmin16[blockIdx.x] = m;   // block b == row group b (16 rows)
    }

    // out = x + var*noise for rows not aliased by scratch (x already in regs)
    if (row >= PREFIX) {
        float var = softplus_of(phi);
        const float* ns = noise + (size_t)row * D + gc * 8;
        float4 nu = *(const float4*)ns, nv = *(const float4*)(ns + 4);
        float4 o0, o1;
        o0.x = u.x + var * nu.x; o0.y = u.y + var * nu.y;
        o0.z = u.z + var * nu.z; o0.w = u.w + var * nu.w;
        o1.x = v.x + var * nv.x; o1.y = v.y + var * nv.y;
        o1.z = v.z + var * nv.z; o1.w = v.w + var * nv.w;
        float* od = out + (size_t)row * D + gc * 8;
        *(float4*)od = o0; *(float4*)(od + 4) = o1;
    }
}

// k2: screened symmetric int8 Gram + fused final log-reduce (last block).
// Screen layers per nt-column:
//   (a) 10-VALU bound: min d2s >= sqiMin + sjMin - 2*max(acc)  (never prunes
//       anything the exact screen would flag, since sqiMin<=sqi, sjMin<=sj,
//       max(acc)>=acc elementwise)
//   (b) exact integer screen (48 VALU) -> (c) exp2 slow path with atomics.
__global__ __launch_bounds__(256, 3) void k2_gram(
        const signed char* __restrict__ q8, const float* __restrict__ phi,
        const int* __restrict__ sqv, float* __restrict__ rowsum,
        const int* __restrict__ sqmin16, int* __restrict__ counter,
        float* __restrict__ out_ixt) {
    __shared__ float red[4];
    __shared__ int sh_last;
    const int tid  = threadIdx.x;
    const int w    = blockIdx.x * 4 + (tid >> 6);
    const int lane = tid & 63;
    const int lrow = lane & 15;
    const int quad = lane >> 4;

    const int cnt = (w < 2112) ? 3 : 2;
    int start     = (w < 2112) ? 3 * w : 2 * w + 2112;
    int ti = 0, rem = start, len = NT64;
    while (rem >= len) { rem -= len; ++ti; --len; }
    int tj = ti + rem;

    float var = softplus_of(phi);
    // p = exp(-0.5*(d2s/256)/var) = exp2(d2s * c2)
    const float c2 = ((-0.5f / var) * 1.4426950408889634f) * (1.f / 256.f);
    // prune iff contribution <= 2^-30  <=>  d2s >= Ts
    const int Ts = (int)ceilf(30.f / (-c2));

    intx4 af[4][2], bf[4][2];
    int   sqi[4][4];
    int   sqiMin = 0;
    int curTi = -1;

    #pragma unroll
    for (int nt = 0; nt < 4; nt++) {
        const signed char* br = q8 + (size_t)(tj * T64 + nt * 16 + lrow) * D + quad * 16;
        bf[nt][0] = *(const intx4*)br;
        bf[nt][1] = *(const intx4*)(br + 64);
    }

    for (int r = 0; r < cnt; ++r) {
        const int iB = ti * T64, jB = tj * T64;

        int sje[4], sjm[4];
        #pragma unroll
        for (int nt = 0; nt < 4; nt++) {
            sje[nt] = sqv[jB + nt * 16 + lrow];
            sjm[nt] = sqmin16[tj * 4 + nt];      // uniform per wave
        }

        if (ti != curTi) {
            #pragma unroll
            for (int mt = 0; mt < 4; mt++) {
                const signed char* ar =
                    q8 + (size_t)(iB + mt * 16 + lrow) * D + quad * 16;
                af[mt][0] = *(const intx4*)ar;
                af[mt][1] = *(const intx4*)(ar + 64);
            }
            #pragma unroll
            for (int mt = 0; mt < 4; mt++)
                #pragma unroll
                for (int reg = 0; reg < 4; reg++)
                    sqi[mt][reg] = sqv[iB + mt * 16 + quad * 4 + reg];
            sqiMin = min(min(sqmin16[ti * 4 + 0], sqmin16[ti * 4 + 1]),
                         min(sqmin16[ti * 4 + 2], sqmin16[ti * 4 + 3]));
            curTi = ti;
        }

        int nti = ti, ntj = tj + 1;
        if (ntj == NT64) { ++nti; ntj = nti; }
        const bool more = (r + 1 < cnt);

        #pragma unroll
        for (int nt = 0; nt < 4; nt++) {
            intx4 acc[4] = {};
            #pragma unroll
            for (int kk = 0; kk < 2; kk++)
                #pragma unroll
                for (int mt = 0; mt < 4; mt++)
                    acc[mt] = __builtin_amdgcn_mfma_i32_16x16x64_i8(
                        af[mt][kk], bf[nt][kk], acc[mt], 0, 0, 0);

            // prefetch next pair's bf[nt] (lands during remaining work)
            if (more) {
                const signed char* br =
                    q8 + (size_t)(ntj * T64 + nt * 16 + lrow) * D + quad * 16;
                bf[nt][0] = *(const intx4*)br;
                bf[nt][1] = *(const intx4*)(br + 64);
            }

            // ---- (a) cheap bound: flag iff 2*max(acc) > sqiMin + sjMin - Ts
            int mx = acc[0][0];
            #pragma unroll
            for (int mt = 0; mt < 4; mt++)
                #pragma unroll
                for (int reg = 0; reg < 4; reg++)
                    mx = max(mx, acc[mt][reg]);   // emits v_max3 chains
            const int Sthr = sqiMin + sjm[nt] - Ts;

            if (__any((mx << 1) > Sthr)) {
                // ---- (b) exact integer screen
                // C/D layout: col = lane&15, row = quad*4 + reg  [learn_hip m89]
                const int sj = sje[nt];
                int mn = 0x7fffffff;
                #pragma unroll
                for (int mt = 0; mt < 4; mt++)
                    #pragma unroll
                    for (int reg = 0; reg < 4; reg++) {
                        int d2s = sqi[mt][reg] + sj - (acc[mt][reg] << 1);
                        mn = min(mn, d2s);
                    }

                if (__any(mn < Ts)) {
                    // ---- (c) exact slow path
                    float colv = 0.f;
                    #pragma unroll
                    for (int mt = 0; mt < 4; mt++)
                        #pragma unroll
                        for (int reg = 0; reg < 4; reg++) {
                            int d2s = sqi[mt][reg] + sj - (acc[mt][reg] << 1);
                            float p = __builtin_amdgcn_exp2f((float)d2s * c2);
                            colv += p;
                            float rv = p;
                            rv += __shfl_xor(rv, 1, 64);
                            rv += __shfl_xor(rv, 2, 64);
                            rv += __shfl_xor(rv, 4, 64);
                            rv += __shfl_xor(rv, 8, 64);
                            if (lrow == 0)
                                atomicAdd(&rowsum[iB + mt * 16 + quad * 4 + reg], rv);
                        }
                    if (ti != tj) {  // symmetric column contribution
                        colv += __shfl_xor(colv, 16, 64);
                        colv += __shfl_xor(colv, 32, 64);
                        if (quad == 0)
                            atomicAdd(&rowsum[jB + nt * 16 + lrow], colv);
                    }
                }
            }
        }

        ti = nti; tj = ntj;
    }

    // ---- fused finalization: last block to finish computes IXT ----
    __syncthreads();
    if (tid == 0) {
        __threadfence();
        int old = __hip_atomic_fetch_add(counter, 1, __ATOMIC_ACQ_REL,
                                         __HIP_MEMORY_SCOPE_AGENT);
        sh_last = (old == K2BLK - 1);
    }
    __syncthreads();
    if (sh_last) {
        float l = 0.f;
        for (int i = tid; i < N; i += 256) {
            float rv = __hip_atomic_load(&rowsum[i], __ATOMIC_RELAXED,
                                         __HIP_MEMORY_SCOPE_AGENT);
            l += logf(rv);
        }
        #pragma unroll
        for (int m = 1; m < 64; m <<= 1) l += __shfl_xor(l, m, 64);
        if ((tid & 63) == 0) red[tid >> 6] = l;
        __syncthreads();
        if (tid == 0) {
            float S = red[0] + red[1] + red[2] + red[3];
            float kde = S / (float)N;
            out_ixt[0] = (logf((float)N) - kde) * 1.4426950408889634f;
        }
    }
}

// k4: out = x + var*noise for the scratch-overlapped prefix rows only.
__global__ __launch_bounds__(256) void k4_out(
        const float* __restrict__ x, const float* __restrict__ phi,
        const float* __restrict__ noise, float* __restrict__ out) {
    int gid = blockIdx.x * 256 + threadIdx.x;   // gid < PREFIX*16
    float var = softplus_of(phi);
    const float* xs = x     + (size_t)gid * 8;
    const float* ns = noise + (size_t)gid * 8;
    float4 u  = *(const float4*)xs, v  = *(const float4*)(xs + 4);
    float4 nu = *(const float4*)ns, nv = *(const float4*)(ns + 4);
    float4 o0, o1;
    o0.x = u.x + var * nu.x; o0.y = u.y + var * nu.y;
    o0.z = u.z + var * nu.z; o0.w = u.w + var * nu.w;
    o1.x = v.x + var * nv.x; o1.y = v.y + var * nv.y;
    o1.z = v.z + var * nv.z; o1.w = v.w + var * nv.w;
    float* od = out + (size_t)gid * 8;
    *(float4*)od = o0; *(float4*)(od + 4) = o1;
}

extern "C" void kernel_launch(void* const* d_in, const int* in_sizes, int n_in,
                              void* d_out, int out_size, void* d_ws, size_t ws_size,
                              hipStream_t stream) {
    const float* x     = (const float*)d_in[0];
    const float* phi   = (const float*)d_in[1];
    const float* noise = (const float*)d_in[2];
    float* out = (float*)d_out;

    // Scratch inside the out region (4 MB available, ~1.07 MB used).
    signed char* q8     = (signed char*)out;                 // N*D bytes
    int*         sqv     = (int*)(out + (size_t)N * D / 4);  // N ints
    float*       rowsum  = (float*)(sqv + N);                // N floats
    int*         sqmin16 = (int*)(rowsum + N);               // N/16 ints
    int*         counter = sqmin16 + (N / 16);               // 1 int

    k1_prep<<<(N * 16) / 256, 256, 0, stream>>>(
        x, phi, noise, out, q8, sqv, rowsum, sqmin16, counter);
    k2_gram<<<K2BLK, 256, 0, stream>>>(
        q8, phi, sqv, rowsum, sqmin16, counter, out + (size_t)N * D);
    k4_out<<<(PREFIX * 16) / 256, 256, 0, stream>>>(x, phi, noise, out);
}

// Round 4
// 98.224 us; speedup vs baseline: 2.6121x; 1.1387x over previous
//
#include <hip/hip_runtime.h>

#define N 8192
#define D 128
#define T64 64
#define NT64 (N / T64)             // 128 tile-rows
#define NPAIR (NT64 * (NT64 + 1) / 2)  // 8256 pairs, 1 wave each
#define PREFIX 2176                // out rows [0,2176) hold scratch; k1 writes the rest
#define TBASE(t) ((t) * NT64 - ((t) * ((t) - 1)) / 2)  // pairs before tile-row t

typedef __attribute__((ext_vector_type(4))) int intx4;
typedef unsigned long long u64;

static __device__ inline float softplus_of(const float* __restrict__ phi) {
    float p = phi[0];
    return (p > 20.f) ? p : log1pf(__expf(p));
}

// ---------------------------------------------------------------------------
// Scratch inside d_out (4 MB region; d_ws never touched):
//   q8     : bytes [0, 1 MB)            = out rows    0..2047
//   sqv    : N ints  (32 KB)            = out rows 2048..2111
//   rowsum : N floats (32 KB)           = out rows 2112..2175
// NO device-scope fences / atomic counters anywhere (round-2/3 lesson: grid
// fences + last-block-done cost 35-170 us on 8 non-coherent XCDs). Cross-
// kernel visibility comes from stream ordering alone.
//   k1: quant + sqv + rowsum=0 + out rows [PREFIX,N)
//   k2: pure screened gram, 1 pair/wave, all loads issued up front
//   k4: blocks 1..132 copy out rows [0,2112); block 0 reduces IXT from rowsum
//       then itself copies rows [2112,2176) (no overlap with the reduce reads)
// ---------------------------------------------------------------------------

__global__ __launch_bounds__(256) void k1_prep(
        const float* __restrict__ x, const float* __restrict__ phi,
        const float* __restrict__ noise, float* __restrict__ out,
        signed char* __restrict__ q8, int* __restrict__ sqv,
        float* __restrict__ rowsum) {
    int tid = threadIdx.x;
    int gid = blockIdx.x * 256 + tid;
    int row = gid >> 4;
    int gc  = gid & 15;

    const float* xs = x + (size_t)row * D + gc * 8;
    float4 u = *(const float4*)xs, v = *(const float4*)(xs + 4);

    float f[8] = {u.x, u.y, u.z, u.w, v.x, v.y, v.z, v.w};
    u64 pack = 0;
    int s = 0;
    #pragma unroll
    for (int k = 0; k < 8; k++) {
        float c = fminf(fmaxf(f[k] * 16.f, -127.f), 127.f);
        int q = (int)rintf(c);
        s += q * q;
        pack |= ((u64)(q & 255)) << (8 * k);
    }
    *(u64*)&q8[(size_t)row * D + gc * 8] = pack;

    #pragma unroll
    for (int m = 1; m < 16; m <<= 1) s += __shfl_xor(s, m, 64);
    if (gc == 0) { sqv[row] = s; rowsum[row] = 0.f; }

    // out = x + var*noise for rows not aliased by scratch (x already in regs)
    if (row >= PREFIX) {
        float var = softplus_of(phi);
        const float* ns = noise + (size_t)row * D + gc * 8;
        float4 nu = *(const float4*)ns, nv = *(const float4*)(ns + 4);
        float4 o0, o1;
        o0.x = u.x + var * nu.x; o0.y = u.y + var * nu.y;
        o0.z = u.z + var * nu.z; o0.w = u.w + var * nu.w;
        o1.x = v.x + var * nv.x; o1.y = v.y + var * nv.y;
        o1.z = v.z + var * nv.z; o1.w = v.w + var * nv.w;
        float* od = out + (size_t)row * D + gc * 8;
        *(float4*)od = o0; *(float4*)(od + 4) = o1;
    }
}

// k2: screened symmetric int8 Gram. ONE 64x64 tile-pair per wave (8256 waves):
// 24 global loads issued back-to-back (single latency exposure), 32 MFMA,
// exact integer screen (d2s = sqi+sj-2dot, exact distance^2 of the quantized
// vectors, scale 256). Pairs with min d2s >= Ts contribute < 2^-30 each and
// are dropped; flagged columns (diagonal tiles + genuinely close pairs) take
// the exact exp2 slow path with atomics. No LDS, no barriers, no fences.
__global__ __launch_bounds__(256, 4) void k2_gram(
        const signed char* __restrict__ q8, const float* __restrict__ phi,
        const int* __restrict__ sqv, float* __restrict__ rowsum) {
    const int tid  = threadIdx.x;
    const int w    = blockIdx.x * 4 + (tid >> 6);   // pair id, 0..8255
    const int lane = tid & 63;
    const int lrow = lane & 15;
    const int quad = lane >> 4;

    // triangular inversion: largest ti with TBASE(ti) <= w  (float path is
    // exact here: values < 2^17 << 2^24; fixup loops absorb sqrt rounding)
    const float fm = (float)(2 * NT64 + 1);
    int ti = (int)((fm - sqrtf(fm * fm - 8.0f * (float)w)) * 0.5f);
    while (TBASE(ti + 1) <= w) ++ti;
    while (TBASE(ti) > w) --ti;
    const int tj = ti + (w - TBASE(ti));

    const float var = softplus_of(phi);
    // p = exp(-0.5*(d2s/256)/var) = exp2(d2s * c2)
    const float c2 = ((-0.5f / var) * 1.4426950408889634f) * (1.f / 256.f);
    // prune iff contribution <= 2^-30  <=>  d2s >= Ts
    const int Ts = (int)ceilf(30.f / (-c2));

    const int iB = ti * T64, jB = tj * T64;

    // ---- issue ALL loads up front (compiler pipelines; one vmcnt wait) ----
    intx4 af[4][2], bf[4][2], sqi[4];
    int   sje[4];
    #pragma unroll
    for (int mt = 0; mt < 4; mt++) {
        const signed char* ar = q8 + (size_t)(iB + mt * 16 + lrow) * D + quad * 16;
        af[mt][0] = *(const intx4*)ar;
        af[mt][1] = *(const intx4*)(ar + 64);
    }
    #pragma unroll
    for (int nt = 0; nt < 4; nt++) {
        const signed char* br = q8 + (size_t)(jB + nt * 16 + lrow) * D + quad * 16;
        bf[nt][0] = *(const intx4*)br;
        bf[nt][1] = *(const intx4*)(br + 64);
    }
    #pragma unroll
    for (int mt = 0; mt < 4; mt++)
        sqi[mt] = *(const intx4*)&sqv[iB + mt * 16 + quad * 4];
    #pragma unroll
    for (int nt = 0; nt < 4; nt++)
        sje[nt] = sqv[jB + nt * 16 + lrow];

    #pragma unroll
    for (int nt = 0; nt < 4; nt++) {
        intx4 acc[4] = {};
        #pragma unroll
        for (int kk = 0; kk < 2; kk++)
            #pragma unroll
            for (int mt = 0; mt < 4; mt++)
                acc[mt] = __builtin_amdgcn_mfma_i32_16x16x64_i8(
                    af[mt][kk], bf[nt][kk], acc[mt], 0, 0, 0);

        // exact integer screen: min d2s over this nt-column
        // C/D layout: col = lane&15, row = quad*4 + reg  [learn_hip m89]
        const int sj = sje[nt];
        int mn = 0x7fffffff;
        #pragma unroll
        for (int mt = 0; mt < 4; mt++)
            #pragma unroll
            for (int reg = 0; reg < 4; reg++) {
                int d2s = sqi[mt][reg] + sj - (acc[mt][reg] << 1);
                mn = min(mn, d2s);
            }

        if (__any(mn < Ts)) {
            // exact slow path (diagonal tiles + genuinely close pairs)
            float colv = 0.f;
            #pragma unroll
            for (int mt = 0; mt < 4; mt++)
                #pragma unroll
                for (int reg = 0; reg < 4; reg++) {
                    int d2s = sqi[mt][reg] + sj - (acc[mt][reg] << 1);
                    float p = __builtin_amdgcn_exp2f((float)d2s * c2);
                    colv += p;
                    float rv = p;
                    rv += __shfl_xor(rv, 1, 64);
                    rv += __shfl_xor(rv, 2, 64);
                    rv += __shfl_xor(rv, 4, 64);
                    rv += __shfl_xor(rv, 8, 64);
                    if (lrow == 0)
                        atomicAdd(&rowsum[iB + mt * 16 + quad * 4 + reg], rv);
                }
            if (ti != tj) {  // symmetric column contribution
                colv += __shfl_xor(colv, 16, 64);
                colv += __shfl_xor(colv, 32, 64);
                if (quad == 0)
                    atomicAdd(&rowsum[jB + nt * 16 + lrow], colv);
            }
        }
    }
}

// k4: block 0 = IXT reduce (rowsum complete via stream order; no fence) then
// copies the rowsum-aliased rows; blocks 1..132 copy out rows [0,2112).
__global__ __launch_bounds__(256) void k4_out(
        const float* __restrict__ x, const float* __restrict__ phi,
        const float* __restrict__ noise, float* out,
        const float* __restrict__ rowsum) {
    const int tid = threadIdx.x;
    const float var = softplus_of(phi);

    if (blockIdx.x == 0) {
        __shared__ float red[4];
        float l = 0.f;
        #pragma unroll 4
        for (int i = tid; i < N; i += 256) l += logf(rowsum[i]);
        #pragma unroll
        for (int m = 1; m < 64; m <<= 1) l += __shfl_xor(l, m, 64);
        if ((tid & 63) == 0) red[tid >> 6] = l;
        __syncthreads();
        if (tid == 0) {
            float S = red[0] + red[1] + red[2] + red[3];
            float kde = S / (float)N;
            out[(size_t)N * D] =
                (logf((float)N) - kde) * 1.4426950408889634f;
        }
        __syncthreads();   // all reduce reads of rowsum done before overwrite
        // copy rows [2112, 2176) — the region aliasing rowsum (8192 floats)
        #pragma unroll
        for (int it = 0; it < 4; it++) {
            int idx = it * 256 + tid;                 // 0..1023 chunks of 8
            size_t off = (size_t)2112 * D + idx * 8;
            const float* xs = x + off;
            const float* ns = noise + off;
            float4 u  = *(const float4*)xs, v  = *(const float4*)(xs + 4);
            float4 nu = *(const float4*)ns, nv = *(const float4*)(ns + 4);
            float4 o0, o1;
            o0.x = u.x + var * nu.x; o0.y = u.y + var * nu.y;
            o0.z = u.z + var * nu.z; o0.w = u.w + var * nu.w;
            o1.x = v.x + var * nv.x; o1.y = v.y + var * nv.y;
            o1.z = v.z + var * nv.z; o1.w = v.w + var * nv.w;
            float* od = out + off;
            *(float4*)od = o0; *(float4*)(od + 4) = o1;
        }
    } else {
        size_t gid = (size_t)(blockIdx.x - 1) * 256 + tid;  // < 2112*16
        const float* xs = x     + gid * 8;
        const float* ns = noise + gid * 8;
        float4 u  = *(const float4*)xs, v  = *(const float4*)(xs + 4);
        float4 nu = *(const float4*)ns, nv = *(const float4*)(ns + 4);
        float4 o0, o1;
        o0.x = u.x + var * nu.x; o0.y = u.y + var * nu.y;
        o0.z = u.z + var * nu.z; o0.w = u.w + var * nu.w;
        o1.x = v.x + var * nv.x; o1.y = v.y + var * nv.y;
        o1.z = v.z + var * nv.z; o1.w = v.w + var * nv.w;
        float* od = out + gid * 8;
        *(float4*)od = o0; *(float4*)(od + 4) = o1;
    }
}

extern "C" void kernel_launch(void* const* d_in, const int* in_sizes, int n_in,
                              void* d_out, int out_size, void* d_ws, size_t ws_size,
                              hipStream_t stream) {
    const float* x     = (const float*)d_in[0];
    const float* phi   = (const float*)d_in[1];
    const float* noise = (const float*)d_in[2];
    float* out = (float*)d_out;

    // Scratch inside the out region (4 MB available, ~1.06 MB used).
    signed char* q8     = (signed char*)out;                 // N*D bytes
    int*         sqv    = (int*)(out + (size_t)N * D / 4);   // N ints
    float*       rowsum = (float*)(sqv + N);                 // N floats

    k1_prep<<<(N * 16) / 256, 256, 0, stream>>>(
        x, phi, noise, out, q8, sqv, rowsum);
    k2_gram<<<NPAIR / 4, 256, 0, stream>>>(q8, phi, sqv, rowsum);
    k4_out<<<1 + (2112 * 16) / 256, 256, 0, stream>>>(
        x, phi, noise, out, rowsum);
}

// Round 5
// 95.313 us; speedup vs baseline: 2.6919x; 1.0305x over previous
//
#include <hip/hip_runtime.h>

#define N 8192
#define D 128
#define T64 64
#define NT64 (N / T64)   // 128 tile-rows; NPAIR = 128*129/2 = 8256 = 2112*3 + 960*2
#define PREFIX 2180      // out rows [0,PREFIX) hold scratch; k1 writes the rest
#define K2BLK 768        // 3072 waves: w<2112 -> 3 pairs, else 2

typedef __attribute__((ext_vector_type(4))) int intx4;
typedef unsigned long long u64;

static __device__ inline float softplus_of(const float* __restrict__ phi) {
    float p = phi[0];
    return (p > 20.f) ? p : log1pf(__expf(p));
}

// ---------------------------------------------------------------------------
// Scratch inside d_out (4 MB region; d_ws never touched):
//   q8      : bytes [0, 1 MB)        = out rows    0..2047
//   sqv     : N ints   (32 KB)       = out rows 2048..2111
//   rowsum  : N floats (32 KB)       = out rows 2112..2175
//   sqmin16 : 512 ints (2 KB)        = out rows 2176..2179  (per-16-row min sqv)
// Total 1,116,160 B = 2180 rows exactly.
// NO device-scope fences / atomic counters (round-2/3 lesson: grid fences and
// last-block-done patterns cost 35-170 us across 8 non-coherent XCDs).
// Cross-kernel visibility via stream ordering only.
//   k1: quant + sqv + sqmin16 + rowsum=0 + out rows [PREFIX,N)
//   k2: screened gram, 3/2 pairs per wave (af reuse + bf prefetch), cheap
//       tile-min screen -> rare exact exp2 slow path
//   k4: blocks 1..132 copy out rows [0,2112); block 0 reduces IXT from rowsum
//       then copies rows [2112,PREFIX)
// ---------------------------------------------------------------------------

__global__ __launch_bounds__(256) void k1_prep(
        const float* __restrict__ x, const float* __restrict__ phi,
        const float* __restrict__ noise, float* __restrict__ out,
        signed char* __restrict__ q8, int* __restrict__ sqv,
        float* __restrict__ rowsum, int* __restrict__ sqmin16) {
    __shared__ int smin[16];
    int tid = threadIdx.x;
    int gid = blockIdx.x * 256 + tid;
    int row = gid >> 4;       // block b covers rows [16b, 16b+16)
    int gc  = gid & 15;

    const float* xs = x + (size_t)row * D + gc * 8;
    float4 u = *(const float4*)xs, v = *(const float4*)(xs + 4);

    float f[8] = {u.x, u.y, u.z, u.w, v.x, v.y, v.z, v.w};
    u64 pack = 0;
    int s = 0;
    #pragma unroll
    for (int k = 0; k < 8; k++) {
        float c = fminf(fmaxf(f[k] * 16.f, -127.f), 127.f);
        int q = (int)rintf(c);
        s += q * q;
        pack |= ((u64)(q & 255)) << (8 * k);
    }
    *(u64*)&q8[(size_t)row * D + gc * 8] = pack;

    #pragma unroll
    for (int m = 1; m < 16; m <<= 1) s += __shfl_xor(s, m, 64);
    if (gc == 0) { sqv[row] = s; rowsum[row] = 0.f; smin[tid >> 4] = s; }
    __syncthreads();
    if (tid == 0) {
        int m = smin[0];
        #pragma unroll
        for (int k = 1; k < 16; k++) m = min(m, smin[k]);
        sqmin16[blockIdx.x] = m;
    }

    // out = x + var*noise for rows not aliased by scratch (x already in regs)
    if (row >= PREFIX) {
        float var = softplus_of(phi);
        const float* ns = noise + (size_t)row * D + gc * 8;
        float4 nu = *(const float4*)ns, nv = *(const float4*)(ns + 4);
        float4 o0, o1;
        o0.x = u.x + var * nu.x; o0.y = u.y + var * nu.y;
        o0.z = u.z + var * nu.z; o0.w = u.w + var * nu.w;
        o1.x = v.x + var * nv.x; o1.y = v.y + var * nv.y;
        o1.z = v.z + var * nv.z; o1.w = v.w + var * nv.w;
        float* od = out + (size_t)row * D + gc * 8;
        *(float4*)od = o0; *(float4*)(od + 4) = o1;
    }
}

// k2: screened symmetric int8 Gram, 3/2 consecutive pairs per wave.
// Per 64x64 pair: 32 MFMA, then ONE cheap screen per nt-column:
//     prune iff 2*max(acc) <= sqiMin + sjMin - Ts
// (d2s = sqi+sj-2acc >= sqiMin+sjMin-2max(acc) elementwise, so every element
// of a pruned column has d2s >= Ts, i.e. contribution < 2^-30 — lossless.)
// Flagged columns (128 diagonal tiles + genuinely close pairs, ~1.6% of all)
// load sqi/sje and take the exact exp2 slow path with atomics.
// No LDS, no barriers, no fences.
__global__ __launch_bounds__(256, 3) void k2_gram(
        const signed char* __restrict__ q8, const float* __restrict__ phi,
        const int* __restrict__ sqv, float* __restrict__ rowsum,
        const int* __restrict__ sqmin16) {
    const int w    = blockIdx.x * 4 + (threadIdx.x >> 6);
    const int lane = threadIdx.x & 63;
    const int lrow = lane & 15;
    const int quad = lane >> 4;

    const int cnt = (w < 2112) ? 3 : 2;
    int start     = (w < 2112) ? 3 * w : 2 * w + 2112;
    int ti = 0, rem = start, len = NT64;
    while (rem >= len) { rem -= len; ++ti; --len; }   // wave-uniform scalar loop
    int tj = ti + rem;

    const float var = softplus_of(phi);
    // p = exp(-0.5*(d2s/256)/var) = exp2(d2s * c2)
    const float c2 = ((-0.5f / var) * 1.4426950408889634f) * (1.f / 256.f);
    // prune iff contribution <= 2^-30  <=>  d2s >= Ts
    const int Ts = (int)ceilf(30.f / (-c2));

    intx4 af[4][2], bf[4][2];
    int sqiMin = 0;
    int curTi = -1;

    // prologue: B fragments for the first pair
    #pragma unroll
    for (int nt = 0; nt < 4; nt++) {
        const signed char* br = q8 + (size_t)(tj * T64 + nt * 16 + lrow) * D + quad * 16;
        bf[nt][0] = *(const intx4*)br;
        bf[nt][1] = *(const intx4*)(br + 64);
    }

    for (int r = 0; r < cnt; ++r) {
        const int iB = ti * T64, jB = tj * T64;

        intx4 mj4 = *(const intx4*)&sqmin16[tj * 4];
        const int sjMin = min(min(mj4[0], mj4[1]), min(mj4[2], mj4[3]));

        if (ti != curTi) {
            #pragma unroll
            for (int mt = 0; mt < 4; mt++) {
                const signed char* ar =
                    q8 + (size_t)(iB + mt * 16 + lrow) * D + quad * 16;
                af[mt][0] = *(const intx4*)ar;
                af[mt][1] = *(const intx4*)(ar + 64);
            }
            intx4 mi4 = *(const intx4*)&sqmin16[ti * 4];
            sqiMin = min(min(mi4[0], mi4[1]), min(mi4[2], mi4[3]));
            curTi = ti;
        }
        const int Sthr = sqiMin + sjMin - Ts;   // wave-uniform

        int nti = ti, ntj = tj + 1;
        if (ntj == NT64) { ++nti; ntj = nti; }
        const bool more = (r + 1 < cnt);

        #pragma unroll
        for (int nt = 0; nt < 4; nt++) {
            intx4 acc[4] = {};
            #pragma unroll
            for (int kk = 0; kk < 2; kk++)
                #pragma unroll
                for (int mt = 0; mt < 4; mt++)
                    acc[mt] = __builtin_amdgcn_mfma_i32_16x16x64_i8(
                        af[mt][kk], bf[nt][kk], acc[mt], 0, 0, 0);

            // bf[nt] consumed -> prefetch next pair's bf[nt] under the
            // remaining work (no barrier ever drains it)
            if (more) {
                const signed char* br =
                    q8 + (size_t)(ntj * T64 + nt * 16 + lrow) * D + quad * 16;
                bf[nt][0] = *(const intx4*)br;
                bf[nt][1] = *(const intx4*)(br + 64);
            }

            // ---- cheap tile-min screen (v_max3 chain, ~11 VALU) ----
            int mx = acc[0][0];
            #pragma unroll
            for (int mt = 0; mt < 4; mt++)
                #pragma unroll
                for (int reg = 0; reg < 4; reg++)
                    mx = max(mx, acc[mt][reg]);

            if (__any((mx << 1) > Sthr)) {
                // ---- exact slow path: load per-row norms now (rare) ----
                // C/D layout: col = lane&15, row = quad*4 + reg  [learn_hip m89]
                const int sj = sqv[jB + nt * 16 + lrow];
                intx4 sqiv[4];
                #pragma unroll
                for (int mt = 0; mt < 4; mt++)
                    sqiv[mt] = *(const intx4*)&sqv[iB + mt * 16 + quad * 4];

                float colv = 0.f;
                #pragma unroll
                for (int mt = 0; mt < 4; mt++)
                    #pragma unroll
                    for (int reg = 0; reg < 4; reg++) {
                        int d2s = sqiv[mt][reg] + sj - (acc[mt][reg] << 1);
                        float p = __builtin_amdgcn_exp2f((float)d2s * c2);
                        colv += p;
                        float rv = p;
                        rv += __shfl_xor(rv, 1, 64);
                        rv += __shfl_xor(rv, 2, 64);
                        rv += __shfl_xor(rv, 4, 64);
                        rv += __shfl_xor(rv, 8, 64);
                        if (lrow == 0)
                            atomicAdd(&rowsum[iB + mt * 16 + quad * 4 + reg], rv);
                    }
                if (ti != tj) {  // symmetric column contribution
                    colv += __shfl_xor(colv, 16, 64);
                    colv += __shfl_xor(colv, 32, 64);
                    if (quad == 0)
                        atomicAdd(&rowsum[jB + nt * 16 + lrow], colv);
                }
            }
        }

        ti = nti; tj = ntj;
    }
}

// k4: block 0 = IXT reduce (rowsum complete via stream order; no fence) then
// copies rows [2112,PREFIX); blocks 1..132 copy out rows [0,2112).
__global__ __launch_bounds__(256) void k4_out(
        const float* __restrict__ x, const float* __restrict__ phi,
        const float* __restrict__ noise, float* out,
        const float* __restrict__ rowsum) {
    const int tid = threadIdx.x;
    const float var = softplus_of(phi);

    if (blockIdx.x == 0) {
        __shared__ float red[4];
        float l = 0.f;
        #pragma unroll 4
        for (int i = tid; i < N; i += 256) l += logf(rowsum[i]);
        #pragma unroll
        for (int m = 1; m < 64; m <<= 1) l += __shfl_xor(l, m, 64);
        if ((tid & 63) == 0) red[tid >> 6] = l;
        __syncthreads();
        if (tid == 0) {
            float S = red[0] + red[1] + red[2] + red[3];
            float kde = S / (float)N;
            out[(size_t)N * D] =
                (logf((float)N) - kde) * 1.4426950408889634f;
        }
        __syncthreads();   // all reduce reads of rowsum done before overwrite
        // copy rows [2112, PREFIX) — (PREFIX-2112)*16 = 1088 chunks of 8
        #pragma unroll
        for (int it = 0; it < 5; it++) {
            int idx = it * 256 + tid;
            if (idx < (PREFIX - 2112) * 16) {
                size_t off = (size_t)2112 * D + (size_t)idx * 8;
                const float* xs = x + off;
                const float* ns = noise + off;
                float4 u  = *(const float4*)xs, v  = *(const float4*)(xs + 4);
                float4 nu = *(const float4*)ns, nv = *(const float4*)(ns + 4);
                float4 o0, o1;
                o0.x = u.x + var * nu.x; o0.y = u.y + var * nu.y;
                o0.z = u.z + var * nu.z; o0.w = u.w + var * nu.w;
                o1.x = v.x + var * nv.x; o1.y = v.y + var * nv.y;
                o1.z = v.z + var * nv.z; o1.w = v.w + var * nv.w;
                float* od = out + off;
                *(float4*)od = o0; *(float4*)(od + 4) = o1;
            }
        }
    } else {
        size_t gid = (size_t)(blockIdx.x - 1) * 256 + tid;  // < 2112*16
        const float* xs = x     + gid * 8;
        const float* ns = noise + gid * 8;
        float4 u  = *(const float4*)xs, v  = *(const float4*)(xs + 4);
        float4 nu = *(const float4*)ns, nv = *(const float4*)(ns + 4);
        float4 o0, o1;
        o0.x = u.x + var * nu.x; o0.y = u.y + var * nu.y;
        o0.z = u.z + var * nu.z; o0.w = u.w + var * nu.w;
        o1.x = v.x + var * nv.x; o1.y = v.y + var * nv.y;
        o1.z = v.z + var * nv.z; o1.w = v.w + var * nv.w;
        float* od = out + gid * 8;
        *(float4*)od = o0; *(float4*)(od + 4) = o1;
    }
}

extern "C" void kernel_launch(void* const* d_in, const int* in_sizes, int n_in,
                              void* d_out, int out_size, void* d_ws, size_t ws_size,
                              hipStream_t stream) {
    const float* x     = (const float*)d_in[0];
    const float* phi   = (const float*)d_in[1];
    const float* noise = (const float*)d_in[2];
    float* out = (float*)d_out;

    // Scratch inside the out region (4 MB available, ~1.07 MB used).
    signed char* q8      = (signed char*)out;                 // N*D bytes
    int*         sqv     = (int*)(out + (size_t)N * D / 4);   // N ints
    float*       rowsum  = (float*)(sqv + N);                 // N floats
    int*         sqmin16 = (int*)(rowsum + N);                // 512 ints

    k1_prep<<<(N * 16) / 256, 256, 0, stream>>>(
        x, phi, noise, out, q8, sqv, rowsum, sqmin16);
    k2_gram<<<K2BLK, 256, 0, stream>>>(q8, phi, sqv, rowsum, sqmin16);
    k4_out<<<1 + (2112 * 16) / 256, 256, 0, stream>>>(
        x, phi, noise, out, rowsum);
}